// Round 6
// baseline (170.302 us; speedup 1.0000x reference)
//
#include <hip/hip_runtime.h>
#include <hip/hip_bf16.h>
#include <math.h>

// Fused SelfAttention (attention over the HEADS axis, per token):
//   qkv = v @ [Wq|Wk|Wv]  (65536x256 @ 256x768, f16 MFMA)
//   per-token 8x8 softmax attention over heads (packed f16 + fp32 softmax)
//   out = x @ Wp + bp       (65536x256 @ 256x256, f16 MFMA)
//
// MFMA orientation: D = A*B, A = W^T-tile (rows = output col n), B = v^T-tile
// (cols = tokens). C/D layout: col(lane&15)=token, row(quad*4+r)=n.
//
// R10: R4 (best: TM=32, 3 blocks/CU via bounds(512,6), 2-pass GEMM1) was
// latency-bound with ~20% on every pipe; R6/R9 showed traffic cuts that cost
// blocks/CU lose. R10 keeps R4's occupancy point exactly and removes its
// three weight cold-starts with a ring-6 seamless stream (24 regs, same as
// R4's wcur+wnxt):
//   - 6-frag prologue issued during v staging (lead = staging + barrier)
//   - steady state: load u+6 at consume u -> ~2 kt of lead
//   - pass0's last 6 consumes refill the ring with pass1's first 6 frags
//     (no pass-boundary cold start)
//   - G2's 4-frag ring primed before barrier-2 (lead spans attention)
// Everything else identical to R4.

#define DIMX      256
#define NH        8
#define HD        32
#define TM        32       // tokens per block
#define NTHREADS  512      // 8 waves
#define QSTRIDE   776      // f16 units per row; 1552 B (16B aligned, banks ok)
#define KT        8        // 256/32 k-tiles
#define NT_QKV    48       // q: 0..15, k: 16..31, v: 32..47

typedef _Float16 f16x8 __attribute__((ext_vector_type(8)));
typedef _Float16 f16x4 __attribute__((ext_vector_type(4)));
typedef _Float16 f16x2 __attribute__((ext_vector_type(2)));
typedef float    f32x4 __attribute__((ext_vector_type(4)));

static __device__ __forceinline__ f16x2 pkrtz(float a, float b) {
    return (f16x2)__builtin_amdgcn_cvt_pkrtz(a, b);
}

// ---------------------------------------------------------------------------
// Prep: pack Wq|Wk|Wv and Wp into MFMA A-operand fragment order, fp32->f16.
// frag[j] = W[kt*32 + quad*8 + j][nt*16 + (lane&15)]
// packed index u = (nt*KT + kt)*64 + lane ; 8 f16 (16 B) per u, contiguous.
// ---------------------------------------------------------------------------
__global__ void pack_weights(const float* __restrict__ Wq,
                             const float* __restrict__ Wk,
                             const float* __restrict__ Wv,
                             const float* __restrict__ Wp,
                             _Float16* __restrict__ pk)
{
    const int QKV_FRAGS = NT_QKV * KT * 64;   // 24576
    int u = blockIdx.x * blockDim.x + threadIdx.x;  // 0..32767
    const float* W;
    int nt, kt, lane;
    if (u < QKV_FRAGS) {
        nt = u / (KT * 64); kt = (u / 64) % KT; lane = u % 64;
        if (nt < 16)      { W = Wq; }
        else if (nt < 32) { W = Wk; nt -= 16; }
        else              { W = Wv; nt -= 32; }
    } else {
        int u2 = u - QKV_FRAGS;
        nt = u2 / (KT * 64); kt = (u2 / 64) % KT; lane = u2 % 64;
        W = Wp;
    }
    const int n  = nt * 16 + (lane & 15);
    const int k0 = kt * 32 + (lane >> 4) * 8;
    f16x8 frag;
#pragma unroll
    for (int j = 0; j < 8; ++j)
        frag[j] = (_Float16)W[(size_t)(k0 + j) * DIMX + n];
    *(f16x8*)(pk + (size_t)u * 8) = frag;
}

// ---------------------------------------------------------------------------
// Main fused kernel. LDS: single 32x776 f16 region (49,664 B -> 3 blocks/CU).
//   phase A: v tile in cols [0,256); phase B: q|k|vv in cols [0,768);
//   phase C: x tile overwrites q-section cols [0,256).
// ---------------------------------------------------------------------------
__global__ __launch_bounds__(NTHREADS, 6)   // 6 waves/EU -> 3 blocks/CU
void fused_attn_mfma(const float* __restrict__ v,
                     const _Float16* __restrict__ Wqkv_pk,
                     const _Float16* __restrict__ Wp_pk,
                     const float* __restrict__ bp,
                     float* __restrict__ out)
{
    __shared__ __align__(16) _Float16 S[TM * QSTRIDE];   // 49664 B

    const int tid   = threadIdx.x;
    const int lane  = tid & 63;
    const int wv_id = tid >> 6;      // wave 0..7
    const int l15   = lane & 15;
    const int quad  = lane >> 4;
    const long token0 = (long)blockIdx.x * TM;

    // pass0 tiles: k-section + low v-section (cols >= 256, no alias with the
    //   v-tile in cols [0,256)) -> immediate writeback.
    // pass1 tiles: {2wv, 2wv+1, 40+wv} (q-section + v-tail) -> writeback
    //   deferred until after the all-reads-done barrier.
    const int tiles0[3] = { 16 + wv_id * 3, 17 + wv_id * 3, 18 + wv_id * 3 };
    const int tiles1[3] = { 2 * wv_id, 2 * wv_id + 1, 40 + wv_id };

    const f16x8* wb  = (const f16x8*)Wqkv_pk + lane;
    const f16x8* wb2 = (const f16x8*)Wp_pk + lane;

    // ---- stage 0: issue v-tile loads, then ring-6 weight prologue ----------
    const float4* src = (const float4*)(v + token0 * DIMX);
    float4 t4[4];
#pragma unroll
    for (int i = 0; i < 4; ++i)
        t4[i] = src[tid + NTHREADS * i];

    // ring-6 weight stream. GEMM1 consume order u = kt*3 + j:
    //   frag(u) = (tile tilesX[u%3], ktf = u/3). Prologue = pass0 u=0..5.
    f16x8 Wr[6];
#pragma unroll
    for (int p = 0; p < 6; ++p)
        Wr[p] = wb[(size_t)(tiles0[p % 3] * KT + p / 3) * 64];

    // v tile fp32 -> f16 -> S cols [0,256)
#pragma unroll
    for (int i = 0; i < 4; ++i) {
        int u = tid + NTHREADS * i;       // 0..2047 float4 slots
        int m = u >> 6;                   // token row (wave-uniform)
        int c = (u & 63) * 4;
        f16x2 lo = pkrtz(t4[i].x, t4[i].y), hi = pkrtz(t4[i].z, t4[i].w);
        f16x4 b4 = { lo.x, lo.y, hi.x, hi.y };
        *(f16x4*)&S[m * QSTRIDE + c] = b4;
    }
    __syncthreads();   // b1: v tile visible in LDS

    // ---- GEMM1 pass0: 3 tiles x 2 tt; ring refills with pass1 frags --------
    f32x4 acc0[2][3];
#pragma unroll
    for (int tt = 0; tt < 2; ++tt)
#pragma unroll
        for (int j = 0; j < 3; ++j)
            acc0[tt][j] = (f32x4){0.f, 0.f, 0.f, 0.f};

#pragma unroll
    for (int kt = 0; kt < KT; ++kt) {
        f16x8 vf[2];
#pragma unroll
        for (int tt = 0; tt < 2; ++tt)
            vf[tt] = *(const f16x8*)&S[(tt * 16 + l15) * QSTRIDE + kt * 32 + quad * 8];
#pragma unroll
        for (int j = 0; j < 3; ++j) {
            const int u = kt * 3 + j;              // compile-time
            f16x8 w = Wr[u % 6];
            if (u + 6 < 24) {
                const int un = u + 6;
                Wr[u % 6] = wb[(size_t)(tiles0[un % 3] * KT + un / 3) * 64];
            } else {
                const int un = u + 6 - 24;         // pass1 frag 0..5
                Wr[u % 6] = wb[(size_t)(tiles1[un % 3] * KT + un / 3) * 64];
            }
            acc0[0][j] = __builtin_amdgcn_mfma_f32_16x16x32_f16(w, vf[0], acc0[0][j], 0, 0, 0);
            acc0[1][j] = __builtin_amdgcn_mfma_f32_16x16x32_f16(w, vf[1], acc0[1][j], 0, 0, 0);
        }
    }

    // immediate writeback (cols >= 256; no alias with v tile)
#pragma unroll
    for (int tt = 0; tt < 2; ++tt)
#pragma unroll
        for (int j = 0; j < 3; ++j) {
            f16x2 a = pkrtz(acc0[tt][j][0], acc0[tt][j][1]);
            f16x2 b = pkrtz(acc0[tt][j][2], acc0[tt][j][3]);
            f16x4 p4 = { a.x, a.y, b.x, b.y };
            *(f16x4*)&S[(tt * 16 + l15) * QSTRIDE + tiles0[j] * 16 + quad * 4] = p4;
        }

    // ---- GEMM1 pass1: ring already primed by pass0's tail ------------------
    f32x4 acc1[2][3];
#pragma unroll
    for (int tt = 0; tt < 2; ++tt)
#pragma unroll
        for (int j = 0; j < 3; ++j)
            acc1[tt][j] = (f32x4){0.f, 0.f, 0.f, 0.f};

#pragma unroll
    for (int kt = 0; kt < KT; ++kt) {
        f16x8 vf[2];
#pragma unroll
        for (int tt = 0; tt < 2; ++tt)
            vf[tt] = *(const f16x8*)&S[(tt * 16 + l15) * QSTRIDE + kt * 32 + quad * 8];
#pragma unroll
        for (int j = 0; j < 3; ++j) {
            const int u = kt * 3 + j;              // compile-time
            f16x8 w = Wr[u % 6];
            if (u + 6 < 24) {
                const int un = u + 6;
                Wr[u % 6] = wb[(size_t)(tiles1[un % 3] * KT + un / 3) * 64];
            }
            acc1[0][j] = __builtin_amdgcn_mfma_f32_16x16x32_f16(w, vf[0], acc1[0][j], 0, 0, 0);
            acc1[1][j] = __builtin_amdgcn_mfma_f32_16x16x32_f16(w, vf[1], acc1[1][j], 0, 0, 0);
        }
    }

    // ---- GEMM2 ring-4 prologue: lead spans writeback + attention -----------
    const int nt0 = wv_id * 2;
    f16x8 W2[4];                       // consume order u2 = kt*2 + j
#pragma unroll
    for (int p = 0; p < 4; ++p)
        W2[p] = wb2[(size_t)((nt0 + (p & 1)) * KT + (p >> 1)) * 64];

    __syncthreads();   // b2: ALL v-tile reads done; q-section may be written

    // deferred pass1 writeback (q-section + v-tail)
#pragma unroll
    for (int tt = 0; tt < 2; ++tt)
#pragma unroll
        for (int j = 0; j < 3; ++j) {
            f16x2 a = pkrtz(acc1[tt][j][0], acc1[tt][j][1]);
            f16x2 b = pkrtz(acc1[tt][j][2], acc1[tt][j][3]);
            f16x4 p4 = { a.x, a.y, b.x, b.y };
            *(f16x4*)&S[(tt * 16 + l15) * QSTRIDE + tiles1[j] * 16 + quad * 4] = p4;
        }
    __syncthreads();   // b3: q|k|vv complete in LDS

    // ---- attention: 16 threads/token = (head h, half d0); packed f16 -------
    {
        const int ta  = tid >> 4;         // token 0..31
        const int sub = tid & 15;
        const int h   = sub >> 1;
        const int d0  = (sub & 1) * 16;   // half of the 32-wide head dim
        const float scale = 0.17677669529663687f;  // 32^-0.5

        const _Float16* qrow  = &S[ta * QSTRIDE + h * HD + d0];
        const _Float16* kbase = &S[ta * QSTRIDE + 256 + d0];
        const _Float16* vbase = &S[ta * QSTRIDE + 512 + d0];

        f16x8 q0 = *(const f16x8*)qrow;
        f16x8 q1 = *(const f16x8*)(qrow + 8);

        float logits[NH];
#pragma unroll
        for (int g = 0; g < NH; ++g) {
            f16x8 k0 = *(const f16x8*)(kbase + g * HD);
            f16x8 k1 = *(const f16x8*)(kbase + g * HD + 8);
            f16x8 p  = q0 * k0;
            p += q1 * k1;
            f16x4 r4 = __builtin_shufflevector(p, p, 0, 1, 2, 3)
                     + __builtin_shufflevector(p, p, 4, 5, 6, 7);
            f16x2 r2 = __builtin_shufflevector(r4, r4, 0, 1)
                     + __builtin_shufflevector(r4, r4, 2, 3);
            logits[g] = (float)r2.x + (float)r2.y;
        }
#pragma unroll
        for (int g = 0; g < NH; ++g)
            logits[g] = (logits[g] + __shfl_xor(logits[g], 1, 64)) * scale;

        float mx = logits[0];
#pragma unroll
        for (int g = 1; g < NH; ++g) mx = fmaxf(mx, logits[g]);
        float se = 0.f;
#pragma unroll
        for (int g = 0; g < NH; ++g) { logits[g] = __expf(logits[g] - mx); se += logits[g]; }
        float inv = 1.f / se;

        f16x8 xa0 = (f16x8)(_Float16)0.f;
        f16x8 xa1 = (f16x8)(_Float16)0.f;
#pragma unroll
        for (int g = 0; g < NH; ++g) {
            _Float16 ph = (_Float16)(logits[g] * inv);
            f16x8 pw = { ph, ph, ph, ph, ph, ph, ph, ph };
            f16x8 v0 = *(const f16x8*)(vbase + g * HD);
            f16x8 v1 = *(const f16x8*)(vbase + g * HD + 8);
            xa0 += pw * v0;
            xa1 += pw * v1;
        }
        __syncthreads();   // b4: all q/k reads done; safe to overwrite q with x
        *(f16x8*)&S[ta * QSTRIDE + h * HD + d0]     = xa0;
        *(f16x8*)&S[ta * QSTRIDE + h * HD + d0 + 8] = xa1;
    }
    __syncthreads();   // b5: x tile complete

    // ---- GEMM2: out = x @ Wp + bp; wave w owns n-tiles {2w, 2w+1} ----------
    {
        f32x4 acc[2][2];   // [tt][j]
#pragma unroll
        for (int tt = 0; tt < 2; ++tt)
#pragma unroll
            for (int j = 0; j < 2; ++j)
                acc[tt][j] = (f32x4){0.f, 0.f, 0.f, 0.f};

#pragma unroll
        for (int kt = 0; kt < KT; ++kt) {
            f16x8 xf[2];
#pragma unroll
            for (int tt = 0; tt < 2; ++tt)
                xf[tt] = *(const f16x8*)&S[(tt * 16 + l15) * QSTRIDE + kt * 32 + quad * 8];
#pragma unroll
            for (int j = 0; j < 2; ++j) {
                const int u2 = kt * 2 + j;         // compile-time
                f16x8 w = W2[u2 % 4];
                if (u2 + 4 < 16)
                    W2[u2 % 4] = wb2[(size_t)((nt0 + j) * KT + (kt + 2)) * 64];
                acc[0][j] = __builtin_amdgcn_mfma_f32_16x16x32_f16(w, xf[0], acc[0][j], 0, 0, 0);
                acc[1][j] = __builtin_amdgcn_mfma_f32_16x16x32_f16(w, xf[1], acc[1][j], 0, 0, 0);
            }
        }
#pragma unroll
        for (int j = 0; j < 2; ++j) {
            f32x4 b = *(const f32x4*)&bp[(nt0 + j) * 16 + quad * 4];
#pragma unroll
            for (int tt = 0; tt < 2; ++tt) {
                f32x4 o = acc[tt][j] + b;
                *(f32x4*)&out[(token0 + tt * 16 + l15) * DIMX + (nt0 + j) * 16 + quad * 4] = o;
            }
        }
    }
}

extern "C" void kernel_launch(void* const* d_in, const int* in_sizes, int n_in,
                              void* d_out, int out_size, void* d_ws, size_t ws_size,
                              hipStream_t stream) {
    const float* v  = (const float*)d_in[0];
    const float* Wq = (const float*)d_in[1];
    const float* Wk = (const float*)d_in[2];
    const float* Wv = (const float*)d_in[3];
    const float* Wp = (const float*)d_in[4];
    const float* bp = (const float*)d_in[5];
    float* out = (float*)d_out;

    _Float16* pk = (_Float16*)d_ws;                // 32768 frags * 16 B = 512 KB
    const _Float16* Wqkv_pk = pk;                  // 24576 frags
    const _Float16* Wp_pk   = pk + (size_t)24576 * 8;

    pack_weights<<<256, 128, 0, stream>>>(Wq, Wk, Wv, Wp, pk);

    const int ntokens = in_sizes[0] / DIMX;        // 65536
    fused_attn_mfma<<<ntokens / TM, NTHREADS, 0, stream>>>(v, Wqkv_pk, Wp_pk, bp, out);
}